// Round 6
// baseline (204.271 us; speedup 1.0000x reference)
//
#include <hip/hip_runtime.h>
#include <math.h>

#define BB 8
#define NN 2048
#define DD 128
#define HH 8

typedef _Float16 v4h __attribute__((ext_vector_type(4)));
typedef _Float16 v8h __attribute__((ext_vector_type(8)));
typedef float    v4f __attribute__((ext_vector_type(4)));
typedef float    v16f __attribute__((ext_vector_type(16)));

__device__ __forceinline__ v4f zero4() { v4f z = {0.f, 0.f, 0.f, 0.f}; return z; }
__device__ __forceinline__ v16f zero16() {
    v16f z;
    #pragma unroll
    for (int i = 0; i < 16; ++i) z[i] = 0.f;
    return z;
}

__device__ __forceinline__ v4f mfma16(v4h a, v4h b, v4f c) {
    return __builtin_amdgcn_mfma_f32_16x16x16f16(a, b, c, 0, 0, 0);
}
__device__ __forceinline__ v16f mfma32(v8h a, v8h b, v16f c) {
    return __builtin_amdgcn_mfma_f32_32x32x16_f16(a, b, c, 0, 0, 0);
}

__device__ __forceinline__ float fexp2(float x) {
#if __has_builtin(__builtin_amdgcn_exp2f)
    return __builtin_amdgcn_exp2f(x);          // v_exp_f32 (2^x)
#else
    return __expf(x * 0.69314718055994531f);
#endif
}

// LOGIT_SCALE = ln400/ln50/4 = 0.38288787333
// QSCALE = 2*LOGIT_SCALE*log2(e): folded into Q rope tables so S = log2(e^{2z})
#define QSCALE 1.10478088f
#define C1F 14.426950408889634f   /* 10*log2e */
#define C2F 28.853900817779268f   /* 20*log2e */

// ---------------- fused QKV projection + RoPE (one m per blockIdx.y) ----------------
// W read as fp32 + inline cvt; RoPE/xpos tables computed per block.
// V^T stored with the MFMA slot permutation baked in (swap k-slots 4..7 <-> 8..11
// within each 16-group) so attn can load V fragments as contiguous v8h.
__global__ __launch_bounds__(256) void proj_rope_kernel(
    const float* __restrict__ q, const float* __restrict__ k, const float* __restrict__ v,
    const float* __restrict__ Wq, const float* __restrict__ Wk, const float* __restrict__ Wv,
    _Float16* __restrict__ Qr, _Float16* __restrict__ Kr, _Float16* __restrict__ VT)
{
    __shared__ __align__(16) _Float16 xb[64][136];
    __shared__ __align__(16) float ctc[64][16];   // cos coefs (pre-scaled)
    __shared__ __align__(16) float cts[64][16];   // sin coefs (pre-scaled)
    const int tid = threadIdx.x;
    const int m  = blockIdx.y;
    const int r0 = blockIdx.x * 64;          // 64 token rows per block
    const int b  = r0 >> 11;
    const int n0 = r0 & 2047;

    const float* s = ((m == 0) ? q : (m == 1) ? k : v) + (size_t)r0 * 128;
    #pragma unroll
    for (int i = 0; i < 8; ++i) {
        int u = tid + i * 256;                       // 2048 float4 chunks
        int row = u >> 5, c4 = (u & 31) * 4;
        v4f f = *(const v4f*)(s + row * 128 + c4);
        v4h hv; hv[0]=(_Float16)f[0]; hv[1]=(_Float16)f[1]; hv[2]=(_Float16)f[2]; hv[3]=(_Float16)f[3];
        *(v4h*)&xb[row][c4] = hv;
    }

    // in-block RoPE/xpos tables (m<2): 512 (token, j) slots, 2 per thread
    if (m < 2) {
        #pragma unroll
        for (int i = 0; i < 2; ++i) {
            int u2 = tid + i * 256;
            int tl = u2 >> 3, j = u2 & 7;
            // invf = 10^(-j/2) via exact 3-select product (no runtime-indexed array)
            float fa = (j & 4) ? 1e-2f : 1.f;
            float fb = (j & 2) ? 1e-1f : 1.f;
            float fc = (j & 1) ? 0.31622776601683794f : 1.f;
            float invf = fa * fb * fc;
            float t = (float)(n0 + tl);
            float freq = t * invf;
            float c = cosf(freq), si = sinf(freq);   // fp32, accurate arg reduction
            float scf = ((float)(2 * j) + 6.4f) / 22.4f;
            float pw  = (t - 1024.0f) / 512.0f;
            float scl = exp2f(pw * log2f(scf));
            float sc  = (m == 0) ? scl * QSCALE : 1.0f / scl;
            float cc = c * sc, ss = si * sc;
            ctc[tl][2 * j]     = cc;
            ctc[tl][2 * j + 1] = cc;
            cts[tl][2 * j]     = ss;
            cts[tl][2 * j + 1] = ss;
        }
    }
    __syncthreads();

    const int w = tid >> 6, lane = tid & 63;
    const int l16 = lane & 15, quad = lane >> 4;

    v4h xf[8];
    #pragma unroll
    for (int kt = 0; kt < 8; ++kt)
        xf[kt] = *(const v4h*)&xb[w * 16 + l16][kt * 16 + quad * 4];
    const float* Wm = (m == 0) ? Wq : (m == 1) ? Wk : Wv;
    v4f acc[8];
    #pragma unroll
    for (int ct = 0; ct < 8; ++ct) acc[ct] = zero4();
    #pragma unroll
    for (int kt = 0; kt < 8; ++kt) {
        #pragma unroll
        for (int ct = 0; ct < 8; ++ct) {
            v4f wv = *(const v4f*)(Wm + (ct * 16 + l16) * 128 + kt * 16 + quad * 4);
            v4h wf; wf[0]=(_Float16)wv[0]; wf[1]=(_Float16)wv[1]; wf[2]=(_Float16)wv[2]; wf[3]=(_Float16)wv[3];
            if (m < 2) acc[ct] = mfma16(wf, xf[kt], acc[ct]);   // D = W * x^T
            else       acc[ct] = mfma16(xf[kt], wf, acc[ct]);   // D = x * W^T
        }
    }
    if (m < 2) {
        const int tl = w * 16 + l16;
        const int n = n0 + tl;
        _Float16* dst = (m == 0 ? Qr : Kr);
        #pragma unroll
        for (int ct = 0; ct < 8; ++ct) {
            v4f cs = *(const v4f*)&ctc[tl][quad * 4];
            v4f sn = *(const v4f*)&cts[tl][quad * 4];
            v4f a = acc[ct];
            v4f rot; rot[0] = -a[1]; rot[1] = a[0]; rot[2] = -a[3]; rot[3] = a[2];
            v4h o;
            #pragma unroll
            for (int r = 0; r < 4; ++r) o[r] = (_Float16)(a[r] * cs[r] + rot[r] * sn[r]);
            *(v4h*)(dst + ((size_t)(b * 8 + ct) * NN + n) * 16 + quad * 4) = o;
        }
    } else {
        // slot-permuted V^T store: within each 16-token group swap quad1<->quad2
        const int quadp = (quad == 1) ? 2 : (quad == 2) ? 1 : quad;
        #pragma unroll
        for (int ct = 0; ct < 8; ++ct) {
            v4f a = acc[ct];
            v4h o;
            #pragma unroll
            for (int r = 0; r < 4; ++r) o[r] = (_Float16)a[r];
            *(v4h*)(VT + ((size_t)(b * 8 + ct) * 16 + l16) * NN + n0 + w * 16 + quadp * 4) = o;
        }
    }
}

// ---------------- fused attention: barrier-free, direct-VMEM fragments ----------------
// K and V fragments are lane-indexed only (identical across waves) -> load them
// straight from global (L2-served; XCD-chunked swizzle keeps each bh's 256KB K/V
// in one XCD's L2). No LDS staging, no __syncthreads, waves fully independent.
// V pre-permuted by proj -> one v8h per fragment; lanes l32>=16 supply the ones
// columns (rowsum) from an immediate. Mask handled by prologue ballot tile-flags:
// fast path = constant addend (bench mask is all-false), slow path stays correct.
__global__ __launch_bounds__(256, 4) void attn_kernel(
    const _Float16* __restrict__ Qr, const _Float16* __restrict__ Kr,
    const _Float16* __restrict__ VT, const unsigned char* __restrict__ mask,
    _Float16* __restrict__ Obuf)
{
    __shared__ __align__(16) _Float16 osm[4 * 768];   // epilogue transpose only

    const int raw = blockIdx.x;
    const int lb  = (raw & 7) * 128 + (raw >> 3);     // XCD-chunk: 8 bh x 16 qt per XCD
    const int bh = lb >> 4;
    const int qt = lb & 15;
    const int b = bh >> 3, h = bh & 7;
    const int q0 = qt * 128;
    const int tid = threadIdx.x;
    const int w = tid >> 6, lane = tid & 63;
    const int l32 = lane & 31, hi = lane >> 5;

    // Q fragment (B-operand): col=q=l32, k(hd)=hi*8+j
    const int qrow = q0 + w * 32 + l32;
    v8h qf = *(const v8h*)(Qr + ((size_t)bh * NN + qrow) * 16 + hi * 8);

    v8h one8;
    #pragma unroll
    for (int i = 0; i < 8; ++i) one8[i] = (_Float16)1.f;

    // per-128-tile mask flags: bits 4t..4t+3 of any4 <-> tile t has masked tokens
    unsigned long long any4;
    {
        const unsigned long long* mq = (const unsigned long long*)(mask + (size_t)b * NN);
        unsigned long long m0 = mq[lane * 4] | mq[lane * 4 + 1] | mq[lane * 4 + 2] | mq[lane * 4 + 3];
        any4 = __ballot(m0 != 0);
    }

    v16f acc = zero16();
    const _Float16* Kb = Kr + (size_t)bh * NN * 16;
    const _Float16* Vb = VT + ((size_t)bh * 16 + l32) * NN;   // dereferenced only when l32<16

    #pragma unroll 1
    for (int it = 0; it < 16; ++it) {
        const int k0 = it * 128;
        const bool mt = ((any4 >> (it * 4)) & 15ull) != 0;

        #pragma unroll
        for (int kc = 0; kc < 4; ++kc) {
            // K fragment: row=k-pos=l32, k-dim=hd=hi*8+j  (contiguous 1KB per wave)
            v8h kf = *(const v8h*)(Kb + (size_t)(k0 + kc * 32 + l32) * 16 + hi * 8);
            // V fragments (pre-permuted): B-cols 0-15 = V^T rows, 16-31 = ones
            v8h vfa = one8, vfb = one8;
            if (l32 < 16) {
                vfa = *(const v8h*)(Vb + k0 + kc * 32 + hi * 8);
                vfb = *(const v8h*)(Vb + k0 + kc * 32 + 16 + hi * 8);
            }
            v16f sv = mfma32(kf, qf, zero16());   // S^T: col=q=l32, row k=(r&3)+8*(r>>2)+4*hi

            float ad[16];
            if (mt) {
                #pragma unroll
                for (int r = 0; r < 16; ++r) {
                    int kk = k0 + kc * 32 + (r >> 2) * 8 + hi * 4 + (r & 3);
                    ad[r] = mask[(size_t)b * NN + kk] ? -1e30f : C1F;
                }
            } else {
                #pragma unroll
                for (int r = 0; r < 16; ++r) ad[r] = C1F;
            }

            float p[16];
            #pragma unroll
            for (int r = 0; r < 16; ++r) {
                float u  = fexp2(sv[r]);                           // e^{2z}
                float rc = __builtin_amdgcn_rcpf(u + 1.f);         // inf-safe
                p[r] = fexp2(__builtin_fmaf(rc, -C2F, ad[r]));
            }
            v8h pa0, pa1;
            #pragma unroll
            for (int j = 0; j < 8; ++j) { pa0[j] = (_Float16)p[j]; pa1[j] = (_Float16)p[8 + j]; }
            acc = mfma32(pa0, vfa, acc);          // rows=q, cols: 0-15 O^T, 16-31 rowsum
            acc = mfma32(pa1, vfb, acc);
        }
    }

    // ---- epilogue: rowsums from partner lanes, per-wave LDS transpose ----
    float rs[16];
    #pragma unroll
    for (int r = 0; r < 16; ++r) rs[r] = __shfl_xor(acc[r], 16, 64);

    _Float16* myOt = osm + w * 768;                    // per-wave [32 q][24] halfs
    if (!(lane & 16)) {                                // lanes holding O columns
        int j = lane & 15;                             // hd
        #pragma unroll
        for (int r = 0; r < 16; ++r) {
            int qr = (r & 3) + 8 * (r >> 2) + 4 * hi;  // q-row within wave tile
            myOt[qr * 24 + j] = (_Float16)(acc[r] * __builtin_amdgcn_rcpf(rs[r]));
        }
    }
    asm volatile("s_waitcnt lgkmcnt(0)" ::: "memory"); // wave-private region: no barrier
    v8h ov = *(const v8h*)(myOt + (lane >> 1) * 24 + (lane & 1) * 8);
    *(v8h*)(Obuf + ((size_t)(b * NN + q0 + w * 32 + (lane >> 1)) * 128) + h * 16 + (lane & 1) * 8) = ov;
}

// ---------------- output projection: out = O @ Wout^T (fp32 out), col-split grid.y ----------------
__global__ __launch_bounds__(256) void outproj_kernel(
    const _Float16* __restrict__ Obuf, const float* __restrict__ Wo,
    float* __restrict__ out)
{
    __shared__ __align__(16) _Float16 ob[64][136];
    const int tid = threadIdx.x;
    const int r0 = blockIdx.x * 64;
    const int ct0 = blockIdx.y * 2;                 // 4-way col split: 32 cols/block
    #pragma unroll
    for (int i = 0; i < 8; ++i) {
        int u = tid + i * 256;
        int row = u >> 5, c4 = (u & 31) * 4;
        *(v4h*)&ob[row][c4] = *(const v4h*)(Obuf + (size_t)(r0 + row) * 128 + c4);
    }
    __syncthreads();
    const int w = tid >> 6, lane = tid & 63;
    const int l16 = lane & 15, quad = lane >> 4;
    v4h af[8];
    #pragma unroll
    for (int kt = 0; kt < 8; ++kt)
        af[kt] = *(const v4h*)&ob[w * 16 + l16][kt * 16 + quad * 4];
    v4f acc[2];
    #pragma unroll
    for (int c = 0; c < 2; ++c) acc[c] = zero4();
    #pragma unroll
    for (int kt = 0; kt < 8; ++kt)
        #pragma unroll
        for (int c = 0; c < 2; ++c) {
            v4f wv = *(const v4f*)(Wo + ((ct0 + c) * 16 + l16) * 128 + kt * 16 + quad * 4);
            v4h wf; wf[0]=(_Float16)wv[0]; wf[1]=(_Float16)wv[1]; wf[2]=(_Float16)wv[2]; wf[3]=(_Float16)wv[3];
            acc[c] = mfma16(af[kt], wf, acc[c]);
        }
    #pragma unroll
    for (int c = 0; c < 2; ++c)
        #pragma unroll
        for (int r = 0; r < 4; ++r)
            out[(size_t)(r0 + w * 16 + quad * 4 + r) * 128 + (ct0 + c) * 16 + l16] = acc[c][r];
}

extern "C" void kernel_launch(void* const* d_in, const int* in_sizes, int n_in,
                              void* d_out, int out_size, void* d_ws, size_t ws_size,
                              hipStream_t stream)
{
    const float* q  = (const float*)d_in[0];
    const float* k  = (const float*)d_in[1];
    const float* v  = (const float*)d_in[2];
    const float* Wq = (const float*)d_in[3];
    const float* Wk = (const float*)d_in[4];
    const float* Wv = (const float*)d_in[5];
    const float* Wo = (const float*)d_in[6];
    const unsigned char* mask = (const unsigned char*)d_in[7];
    float* out = (float*)d_out;

    char* ws = (char*)d_ws;
    _Float16* Qr   = (_Float16*)(ws);                 //   4 MB  (B,H,N,16)
    _Float16* Kr   = (_Float16*)(ws + 4194304);       //   4 MB
    _Float16* VTd  = (_Float16*)(ws + 8388608);       //   4 MB  (B,H,16,N) slot-permuted
    _Float16* Obuf = (_Float16*)(ws + 12582912);      //   4 MB  (B*N,128)

    proj_rope_kernel<<<dim3(256, 3), 256, 0, stream>>>(q, k, v, Wq, Wk, Wv, Qr, Kr, VTd);
    attn_kernel<<<1024, 256, 0, stream>>>(Qr, Kr, VTd, mask, Obuf);
    outproj_kernel<<<dim3(256, 4), 256, 0, stream>>>(Obuf, Wo, out);
}

// Round 7
// 195.900 us; speedup vs baseline: 1.0427x; 1.0427x over previous
//
#include <hip/hip_runtime.h>
#include <math.h>

#define BB 8
#define NN 2048
#define DD 128
#define HH 8

typedef _Float16 v4h __attribute__((ext_vector_type(4)));
typedef _Float16 v8h __attribute__((ext_vector_type(8)));
typedef float    v4f __attribute__((ext_vector_type(4)));
typedef float    v16f __attribute__((ext_vector_type(16)));

__device__ __forceinline__ v4f zero4() { v4f z = {0.f, 0.f, 0.f, 0.f}; return z; }
__device__ __forceinline__ v16f zero16() {
    v16f z;
    #pragma unroll
    for (int i = 0; i < 16; ++i) z[i] = 0.f;
    return z;
}

__device__ __forceinline__ v4f mfma16(v4h a, v4h b, v4f c) {
    return __builtin_amdgcn_mfma_f32_16x16x16f16(a, b, c, 0, 0, 0);
}
__device__ __forceinline__ v16f mfma32(v8h a, v8h b, v16f c) {
    return __builtin_amdgcn_mfma_f32_32x32x16_f16(a, b, c, 0, 0, 0);
}

__device__ __forceinline__ float fexp2(float x) {
#if __has_builtin(__builtin_amdgcn_exp2f)
    return __builtin_amdgcn_exp2f(x);          // v_exp_f32 (2^x)
#else
    return __expf(x * 0.69314718055994531f);
#endif
}

// LOGIT_SCALE = ln400/ln50/4 = 0.38288787333
// QSCALE = 2*LOGIT_SCALE*log2(e): folded into Q rope tables so S = log2(e^{2z})
#define QSCALE 1.10478088f
#define C1F 14.426950408889634f   /* 10*log2e */
#define C2F 28.853900817779268f   /* 20*log2e */

// ---------------- fused QKV projection + RoPE (one m per blockIdx.y) ----------------
// W read as fp32 + inline cvt; RoPE/xpos tables computed per block.
// V^T stored with the MFMA slot permutation baked in (swap k-slots 4..7 <-> 8..11
// within each 16-group) so attn can stage V fragments as contiguous v8h.
__global__ __launch_bounds__(256) void proj_rope_kernel(
    const float* __restrict__ q, const float* __restrict__ k, const float* __restrict__ v,
    const float* __restrict__ Wq, const float* __restrict__ Wk, const float* __restrict__ Wv,
    _Float16* __restrict__ Qr, _Float16* __restrict__ Kr, _Float16* __restrict__ VT)
{
    __shared__ __align__(16) _Float16 xb[64][136];
    __shared__ __align__(16) float ctc[64][16];   // cos coefs (pre-scaled)
    __shared__ __align__(16) float cts[64][16];   // sin coefs (pre-scaled)
    const int tid = threadIdx.x;
    const int m  = blockIdx.y;
    const int r0 = blockIdx.x * 64;          // 64 token rows per block
    const int b  = r0 >> 11;
    const int n0 = r0 & 2047;

    const float* s = ((m == 0) ? q : (m == 1) ? k : v) + (size_t)r0 * 128;
    #pragma unroll
    for (int i = 0; i < 8; ++i) {
        int u = tid + i * 256;                       // 2048 float4 chunks
        int row = u >> 5, c4 = (u & 31) * 4;
        v4f f = *(const v4f*)(s + row * 128 + c4);
        v4h hv; hv[0]=(_Float16)f[0]; hv[1]=(_Float16)f[1]; hv[2]=(_Float16)f[2]; hv[3]=(_Float16)f[3];
        *(v4h*)&xb[row][c4] = hv;
    }

    // in-block RoPE/xpos tables (m<2): 512 (token, j) slots, 2 per thread
    if (m < 2) {
        #pragma unroll
        for (int i = 0; i < 2; ++i) {
            int u2 = tid + i * 256;
            int tl = u2 >> 3, j = u2 & 7;
            // invf = 10^(-j/2) via exact 3-select product (no runtime-indexed array)
            float fa = (j & 4) ? 1e-2f : 1.f;
            float fb = (j & 2) ? 1e-1f : 1.f;
            float fc = (j & 1) ? 0.31622776601683794f : 1.f;
            float invf = fa * fb * fc;
            float t = (float)(n0 + tl);
            float freq = t * invf;
            float c = cosf(freq), si = sinf(freq);   // fp32, accurate arg reduction
            float scf = ((float)(2 * j) + 6.4f) / 22.4f;
            float pw  = (t - 1024.0f) / 512.0f;
            float scl = exp2f(pw * log2f(scf));
            float sc  = (m == 0) ? scl * QSCALE : 1.0f / scl;
            float cc = c * sc, ss = si * sc;
            ctc[tl][2 * j]     = cc;
            ctc[tl][2 * j + 1] = cc;
            cts[tl][2 * j]     = ss;
            cts[tl][2 * j + 1] = ss;
        }
    }
    __syncthreads();

    const int w = tid >> 6, lane = tid & 63;
    const int l16 = lane & 15, quad = lane >> 4;

    v4h xf[8];
    #pragma unroll
    for (int kt = 0; kt < 8; ++kt)
        xf[kt] = *(const v4h*)&xb[w * 16 + l16][kt * 16 + quad * 4];
    const float* Wm = (m == 0) ? Wq : (m == 1) ? Wk : Wv;
    v4f acc[8];
    #pragma unroll
    for (int ct = 0; ct < 8; ++ct) acc[ct] = zero4();
    #pragma unroll
    for (int kt = 0; kt < 8; ++kt) {
        #pragma unroll
        for (int ct = 0; ct < 8; ++ct) {
            v4f wv = *(const v4f*)(Wm + (ct * 16 + l16) * 128 + kt * 16 + quad * 4);
            v4h wf; wf[0]=(_Float16)wv[0]; wf[1]=(_Float16)wv[1]; wf[2]=(_Float16)wv[2]; wf[3]=(_Float16)wv[3];
            if (m < 2) acc[ct] = mfma16(wf, xf[kt], acc[ct]);   // D = W * x^T
            else       acc[ct] = mfma16(xf[kt], wf, acc[ct]);   // D = x * W^T
        }
    }
    if (m < 2) {
        const int tl = w * 16 + l16;
        const int n = n0 + tl;
        _Float16* dst = (m == 0 ? Qr : Kr);
        #pragma unroll
        for (int ct = 0; ct < 8; ++ct) {
            v4f cs = *(const v4f*)&ctc[tl][quad * 4];
            v4f sn = *(const v4f*)&cts[tl][quad * 4];
            v4f a = acc[ct];
            v4f rot; rot[0] = -a[1]; rot[1] = a[0]; rot[2] = -a[3]; rot[3] = a[2];
            v4h o;
            #pragma unroll
            for (int r = 0; r < 4; ++r) o[r] = (_Float16)(a[r] * cs[r] + rot[r] * sn[r]);
            *(v4h*)(dst + ((size_t)(b * 8 + ct) * NN + n) * 16 + quad * 4) = o;
        }
    } else {
        // slot-permuted V^T store: within each 16-token group swap quad1<->quad2
        const int quadp = (quad == 1) ? 2 : (quad == 2) ? 1 : quad;
        #pragma unroll
        for (int ct = 0; ct < 8; ++ct) {
            v4f a = acc[ct];
            v4h o;
            #pragma unroll
            for (int r = 0; r < 4; ++r) o[r] = (_Float16)a[r];
            *(v4h*)(VT + ((size_t)(b * 8 + ct) * 16 + l16) * NN + n0 + w * 16 + quadp * 4) = o;
        }
    }
}

// ---------------- fused attention (R4 structure + XCD swizzle + ballot mask) ----------------
// 256 thr / 4 waves / full K; single LDS buffer; reg-prefetch (issue next tile's
// globals between ds_write and the barrier so latency hides under compute).
// XCD-chunked blockIdx swizzle: 8 bh x 16 qt per XCD -> K/V L2-resident per XCD.
// Mask via prologue ballot tile-flags (no LDS addend array): fast path uses SGPR
// constant C1F in the fma; slow path reads mask bytes (correctness preserved).
__global__ __launch_bounds__(256, 4) void attn_kernel(
    const _Float16* __restrict__ Qr, const _Float16* __restrict__ Kr,
    const _Float16* __restrict__ VT, const unsigned char* __restrict__ mask,
    _Float16* __restrict__ Obuf)
{
    __shared__ __align__(16) char smem[14848];
    _Float16* Kt = (_Float16*)smem;              // [128][24] halfs (row stride 48 B)
    _Float16* Ve = (_Float16*)(smem + 6144);     // [32][136] halfs (rows 0-15 V, 16-31 ones)

    const int raw = blockIdx.x;
    const int lb  = (raw & 7) * 128 + (raw >> 3);    // XCD chunk: 8 bh x 16 qt per XCD
    const int bh = lb >> 4;                      // 64 (b,h)
    const int qt = lb & 15;                      // 16 q-tiles of 128
    const int b = bh >> 3, h = bh & 7;
    const int q0 = qt * 128;
    const int tid = threadIdx.x;
    const int w = tid >> 6, lane = tid & 63;
    const int l32 = lane & 31, hi = lane >> 5;

    // Q fragment (B-operand): col=q=l32, k(hd)=hi*8+j
    const int qrow = q0 + w * 32 + l32;
    v8h qf = *(const v8h*)(Qr + ((size_t)bh * NN + qrow) * 16 + hi * 8);

    // ones rows of Ve (rows 16-31), written once
    {
        v8h one8;
        #pragma unroll
        for (int i = 0; i < 8; ++i) one8[i] = (_Float16)1.f;
        *(v8h*)(Ve + (16 + (tid >> 4)) * 136 + (tid & 15) * 8) = one8;
    }

    // per-128-tile mask flags: bits 4t..4t+3 of any4 <-> tile t has masked tokens
    unsigned long long any4;
    {
        const unsigned long long* mq = (const unsigned long long*)(mask + (size_t)b * NN);
        unsigned long long m0 = mq[lane * 4] | mq[lane * 4 + 1] | mq[lane * 4 + 2] | mq[lane * 4 + 3];
        any4 = __ballot(m0 != 0);
    }

    v16f acc = zero16();

    const int krow = tid >> 1, kpar = tid & 1;   // K staging: 128 rows x 2 halves
    const int vhd = tid >> 4, vg = tid & 15;     // V staging: 16 hd x 16 k-groups of 8
    const _Float16* Kbase = Kr + (size_t)bh * NN * 16;
    const _Float16* Vbase = VT + ((size_t)bh * 16 + vhd) * NN;   // pre-permuted layout
    const unsigned char* mbase = mask + (size_t)b * NN;

    // ---- prologue: prefetch tile 0 into registers ----
    v8h kv = *(const v8h*)(Kbase + (size_t)krow * 16 + kpar * 8);
    v8h vv = *(const v8h*)(Vbase + vg * 8);

    for (int it = 0; it < 16; ++it) {
        __syncthreads();                         // previous tile's reads complete
        // ---- stage current tile from regs ----
        *(v8h*)(Kt + krow * 24 + kpar * 8) = kv;
        *(v8h*)(Ve + vhd * 136 + vg * 8) = vv;   // V pre-permuted: direct copy
        // ---- issue next tile's global loads (latency hides under compute) ----
        if (it < 15) {
            const int k0n = (it + 1) * 128;
            kv = *(const v8h*)(Kbase + (size_t)(k0n + krow) * 16 + kpar * 8);
            vv = *(const v8h*)(Vbase + k0n + vg * 8);
        }
        __syncthreads();                         // staging visible

        const int k0 = it * 128;
        const bool mt = ((any4 >> (it * 4)) & 15ull) != 0;

        #pragma unroll
        for (int kc = 0; kc < 4; ++kc) {
            // A = K rows (row=k-pos=l32 within chunk, k-dim=hd=hi*8+j)
            v8h kf = *(const v8h*)(Kt + (kc * 32 + l32) * 24 + hi * 8);
            v16f sv = mfma32(kf, qf, zero16());   // S^T: col=q=l32, row k=(r&3)+8*(r>>2)+4*hi

            float ad[16];
            if (mt) {
                #pragma unroll
                for (int r = 0; r < 16; ++r) {
                    int kk = k0 + kc * 32 + (r >> 2) * 8 + hi * 4 + (r & 3);
                    ad[r] = mbase[kk] ? -1e30f : C1F;
                }
            } else {
                #pragma unroll
                for (int r = 0; r < 16; ++r) ad[r] = C1F;
            }

            float p[16];
            #pragma unroll
            for (int r = 0; r < 16; ++r) {
                float u  = fexp2(sv[r]);                           // e^{2z}
                float rc = __builtin_amdgcn_rcpf(u + 1.f);         // inf-safe
                p[r] = fexp2(__builtin_fmaf(rc, -C2F, ad[r]));
            }

            #pragma unroll
            for (int c2 = 0; c2 < 2; ++c2) {
                v8h pa;
                #pragma unroll
                for (int j = 0; j < 8; ++j) pa[j] = (_Float16)p[c2 * 8 + j];
                v8h vf = *(const v8h*)(Ve + l32 * 136 + (kc * 2 + c2) * 16 + hi * 8);
                acc = mfma32(pa, vf, acc);         // rows=q, cols: 0-15 O^T, 16-31 rowsum
            }
        }
    }

    // ---- epilogue ----
    // row sums live in partner lanes (col >= 16); same reg index
    float rs[16];
    #pragma unroll
    for (int r = 0; r < 16; ++r) rs[r] = __shfl_xor(acc[r], 16, 64);

    __syncthreads();                                   // all K-tile reads done: safe to alias
    _Float16* myOt = (_Float16*)smem + w * 768;        // per-wave [32 q][24] halfs over Kt
    if (!(lane & 16)) {                                // lanes holding O columns
        int j = lane & 15;                             // hd
        #pragma unroll
        for (int r = 0; r < 16; ++r) {
            int qr = (r & 3) + 8 * (r >> 2) + 4 * hi;  // q-row within wave tile
            myOt[qr * 24 + j] = (_Float16)(acc[r] * __builtin_amdgcn_rcpf(rs[r]));
        }
    }
    asm volatile("s_waitcnt lgkmcnt(0)" ::: "memory"); // wave-private region: no barrier needed
    v8h ov = *(const v8h*)(myOt + (lane >> 1) * 24 + (lane & 1) * 8);
    *(v8h*)(Obuf + ((size_t)(b * NN + q0 + w * 32 + (lane >> 1)) * 128) + h * 16 + (lane & 1) * 8) = ov;
}

// ---------------- output projection: out = O @ Wout^T (fp32 out), col-split grid.y ----------------
__global__ __launch_bounds__(256) void outproj_kernel(
    const _Float16* __restrict__ Obuf, const float* __restrict__ Wo,
    float* __restrict__ out)
{
    __shared__ __align__(16) _Float16 ob[64][136];
    const int tid = threadIdx.x;
    const int r0 = blockIdx.x * 64;
    const int ct0 = blockIdx.y * 2;                 // 4-way col split: 32 cols/block
    #pragma unroll
    for (int i = 0; i < 8; ++i) {
        int u = tid + i * 256;
        int row = u >> 5, c4 = (u & 31) * 4;
        *(v4h*)&ob[row][c4] = *(const v4h*)(Obuf + (size_t)(r0 + row) * 128 + c4);
    }
    __syncthreads();
    const int w = tid >> 6, lane = tid & 63;
    const int l16 = lane & 15, quad = lane >> 4;
    v4h af[8];
    #pragma unroll
    for (int kt = 0; kt < 8; ++kt)
        af[kt] = *(const v4h*)&ob[w * 16 + l16][kt * 16 + quad * 4];
    v4f acc[2];
    #pragma unroll
    for (int c = 0; c < 2; ++c) acc[c] = zero4();
    #pragma unroll
    for (int kt = 0; kt < 8; ++kt)
        #pragma unroll
        for (int c = 0; c < 2; ++c) {
            v4f wv = *(const v4f*)(Wo + ((ct0 + c) * 16 + l16) * 128 + kt * 16 + quad * 4);
            v4h wf; wf[0]=(_Float16)wv[0]; wf[1]=(_Float16)wv[1]; wf[2]=(_Float16)wv[2]; wf[3]=(_Float16)wv[3];
            acc[c] = mfma16(af[kt], wf, acc[c]);
        }
    #pragma unroll
    for (int c = 0; c < 2; ++c)
        #pragma unroll
        for (int r = 0; r < 4; ++r)
            out[(size_t)(r0 + w * 16 + quad * 4 + r) * 128 + (ct0 + c) * 16 + l16] = acc[c][r];
}

extern "C" void kernel_launch(void* const* d_in, const int* in_sizes, int n_in,
                              void* d_out, int out_size, void* d_ws, size_t ws_size,
                              hipStream_t stream)
{
    const float* q  = (const float*)d_in[0];
    const float* k  = (const float*)d_in[1];
    const float* v  = (const float*)d_in[2];
    const float* Wq = (const float*)d_in[3];
    const float* Wk = (const float*)d_in[4];
    const float* Wv = (const float*)d_in[5];
    const float* Wo = (const float*)d_in[6];
    const unsigned char* mask = (const unsigned char*)d_in[7];
    float* out = (float*)d_out;

    char* ws = (char*)d_ws;
    _Float16* Qr   = (_Float16*)(ws);                 //   4 MB  (B,H,N,16)
    _Float16* Kr   = (_Float16*)(ws + 4194304);       //   4 MB
    _Float16* VTd  = (_Float16*)(ws + 8388608);       //   4 MB  (B,H,16,N) slot-permuted
    _Float16* Obuf = (_Float16*)(ws + 12582912);      //   4 MB  (B*N,128)

    proj_rope_kernel<<<dim3(256, 3), 256, 0, stream>>>(q, k, v, Wq, Wk, Wv, Qr, Kr, VTd);
    attn_kernel<<<1024, 256, 0, stream>>>(Qr, Kr, VTd, mask, Obuf);
    outproj_kernel<<<dim3(256, 4), 256, 0, stream>>>(Obuf, Wo, out);
}

// Round 8
// 191.519 us; speedup vs baseline: 1.0666x; 1.0229x over previous
//
#include <hip/hip_runtime.h>
#include <math.h>

#define BB 8
#define NN 2048
#define DD 128
#define HH 8

typedef _Float16 v4h __attribute__((ext_vector_type(4)));
typedef _Float16 v8h __attribute__((ext_vector_type(8)));
typedef float    v4f __attribute__((ext_vector_type(4)));
typedef float    v16f __attribute__((ext_vector_type(16)));

__device__ __forceinline__ v4f zero4() { v4f z = {0.f, 0.f, 0.f, 0.f}; return z; }
__device__ __forceinline__ v16f zero16() {
    v16f z;
    #pragma unroll
    for (int i = 0; i < 16; ++i) z[i] = 0.f;
    return z;
}

__device__ __forceinline__ v4f mfma16(v4h a, v4h b, v4f c) {
    return __builtin_amdgcn_mfma_f32_16x16x16f16(a, b, c, 0, 0, 0);
}
__device__ __forceinline__ v16f mfma32(v8h a, v8h b, v16f c) {
    return __builtin_amdgcn_mfma_f32_32x32x16_f16(a, b, c, 0, 0, 0);
}

__device__ __forceinline__ float fexp2(float x) {
#if __has_builtin(__builtin_amdgcn_exp2f)
    return __builtin_amdgcn_exp2f(x);          // v_exp_f32 (2^x)
#else
    return __expf(x * 0.69314718055994531f);
#endif
}

// LOGIT_SCALE = ln400/ln50/4 = 0.38288787333
// QSCALE = 2*LOGIT_SCALE*log2(e): folded into Q rope tables so S = log2(e^{2z})
#define QSCALE 1.10478088f
#define C1F 14.426950408889634f   /* 10*log2e */
#define C2F 28.853900817779268f   /* 20*log2e */

// ---------------- fused QKV projection + RoPE (one m per blockIdx.y) ----------------
// W read as fp32 + inline cvt; RoPE/xpos tables computed per block.
// V^T stored with the MFMA slot permutation baked in (swap k-slots 4..7 <-> 8..11
// within each 16-group) so attn can stage V fragments as contiguous v8h.
__global__ __launch_bounds__(256) void proj_rope_kernel(
    const float* __restrict__ q, const float* __restrict__ k, const float* __restrict__ v,
    const float* __restrict__ Wq, const float* __restrict__ Wk, const float* __restrict__ Wv,
    _Float16* __restrict__ Qr, _Float16* __restrict__ Kr, _Float16* __restrict__ VT)
{
    __shared__ __align__(16) _Float16 xb[64][136];
    __shared__ __align__(16) float ctc[64][16];   // cos coefs (pre-scaled)
    __shared__ __align__(16) float cts[64][16];   // sin coefs (pre-scaled)
    const int tid = threadIdx.x;
    const int m  = blockIdx.y;
    const int r0 = blockIdx.x * 64;          // 64 token rows per block
    const int b  = r0 >> 11;
    const int n0 = r0 & 2047;

    const float* s = ((m == 0) ? q : (m == 1) ? k : v) + (size_t)r0 * 128;
    #pragma unroll
    for (int i = 0; i < 8; ++i) {
        int u = tid + i * 256;                       // 2048 float4 chunks
        int row = u >> 5, c4 = (u & 31) * 4;
        v4f f = *(const v4f*)(s + row * 128 + c4);
        v4h hv; hv[0]=(_Float16)f[0]; hv[1]=(_Float16)f[1]; hv[2]=(_Float16)f[2]; hv[3]=(_Float16)f[3];
        *(v4h*)&xb[row][c4] = hv;
    }

    // in-block RoPE/xpos tables (m<2): 512 (token, j) slots, 2 per thread
    if (m < 2) {
        #pragma unroll
        for (int i = 0; i < 2; ++i) {
            int u2 = tid + i * 256;
            int tl = u2 >> 3, j = u2 & 7;
            // invf = 10^(-j/2) via exact 3-select product (no runtime-indexed array)
            float fa = (j & 4) ? 1e-2f : 1.f;
            float fb = (j & 2) ? 1e-1f : 1.f;
            float fc = (j & 1) ? 0.31622776601683794f : 1.f;
            float invf = fa * fb * fc;
            float t = (float)(n0 + tl);
            float freq = t * invf;
            float c = cosf(freq), si = sinf(freq);   // fp32, accurate arg reduction
            float scf = ((float)(2 * j) + 6.4f) / 22.4f;
            float pw  = (t - 1024.0f) / 512.0f;
            float scl = exp2f(pw * log2f(scf));
            float sc  = (m == 0) ? scl * QSCALE : 1.0f / scl;
            float cc = c * sc, ss = si * sc;
            ctc[tl][2 * j]     = cc;
            ctc[tl][2 * j + 1] = cc;
            cts[tl][2 * j]     = ss;
            cts[tl][2 * j + 1] = ss;
        }
    }
    __syncthreads();

    const int w = tid >> 6, lane = tid & 63;
    const int l16 = lane & 15, quad = lane >> 4;

    v4h xf[8];
    #pragma unroll
    for (int kt = 0; kt < 8; ++kt)
        xf[kt] = *(const v4h*)&xb[w * 16 + l16][kt * 16 + quad * 4];
    const float* Wm = (m == 0) ? Wq : (m == 1) ? Wk : Wv;
    v4f acc[8];
    #pragma unroll
    for (int ct = 0; ct < 8; ++ct) acc[ct] = zero4();
    #pragma unroll
    for (int kt = 0; kt < 8; ++kt) {
        #pragma unroll
        for (int ct = 0; ct < 8; ++ct) {
            v4f wv = *(const v4f*)(Wm + (ct * 16 + l16) * 128 + kt * 16 + quad * 4);
            v4h wf; wf[0]=(_Float16)wv[0]; wf[1]=(_Float16)wv[1]; wf[2]=(_Float16)wv[2]; wf[3]=(_Float16)wv[3];
            if (m < 2) acc[ct] = mfma16(wf, xf[kt], acc[ct]);   // D = W * x^T
            else       acc[ct] = mfma16(xf[kt], wf, acc[ct]);   // D = x * W^T
        }
    }
    if (m < 2) {
        const int tl = w * 16 + l16;
        const int n = n0 + tl;
        _Float16* dst = (m == 0 ? Qr : Kr);
        #pragma unroll
        for (int ct = 0; ct < 8; ++ct) {
            v4f cs = *(const v4f*)&ctc[tl][quad * 4];
            v4f sn = *(const v4f*)&cts[tl][quad * 4];
            v4f a = acc[ct];
            v4f rot; rot[0] = -a[1]; rot[1] = a[0]; rot[2] = -a[3]; rot[3] = a[2];
            v4h o;
            #pragma unroll
            for (int r = 0; r < 4; ++r) o[r] = (_Float16)(a[r] * cs[r] + rot[r] * sn[r]);
            *(v4h*)(dst + ((size_t)(b * 8 + ct) * NN + n) * 16 + quad * 4) = o;
        }
    } else {
        // slot-permuted V^T store: within each 16-token group swap quad1<->quad2
        const int quadp = (quad == 1) ? 2 : (quad == 2) ? 1 : quad;
        #pragma unroll
        for (int ct = 0; ct < 8; ++ct) {
            v4f a = acc[ct];
            v4h o;
            #pragma unroll
            for (int r = 0; r < 4; ++r) o[r] = (_Float16)a[r];
            *(v4h*)(VT + ((size_t)(b * 8 + ct) * 16 + l16) * NN + n0 + w * 16 + quadp * 4) = o;
        }
    }
}

// ---------------- fused attention (R4 structure, wide-ILP transform) ----------------
// 256 thr / 4 waves / full K; single LDS buffer; reg-prefetch; natural blockIdx
// (R7's XCD swizzle reverted). Transform split into staged passes u[16]->t[16]->p[16]
// so all 16 transcendental chains stay live (R7's VGPR=44 showed the compiler had
// serialized them ~4-wide, exposing quarter-rate trans latency -> VALUBusy cap 74%).
// Mask via prologue ballot tile-flags; V pre-permuted by proj (direct v8h staging).
__global__ __launch_bounds__(256, 4) void attn_kernel(
    const _Float16* __restrict__ Qr, const _Float16* __restrict__ Kr,
    const _Float16* __restrict__ VT, const unsigned char* __restrict__ mask,
    _Float16* __restrict__ Obuf)
{
    __shared__ __align__(16) char smem[14848];
    _Float16* Kt = (_Float16*)smem;              // [128][24] halfs (row stride 48 B)
    _Float16* Ve = (_Float16*)(smem + 6144);     // [32][136] halfs (rows 0-15 V, 16-31 ones)

    const int bh = blockIdx.x >> 4;              // 64 (b,h)
    const int qt = blockIdx.x & 15;              // 16 q-tiles of 128
    const int b = bh >> 3, h = bh & 7;
    const int q0 = qt * 128;
    const int tid = threadIdx.x;
    const int w = tid >> 6, lane = tid & 63;
    const int l32 = lane & 31, hi = lane >> 5;

    // Q fragment (B-operand): col=q=l32, k(hd)=hi*8+j
    const int qrow = q0 + w * 32 + l32;
    v8h qf = *(const v8h*)(Qr + ((size_t)bh * NN + qrow) * 16 + hi * 8);

    // ones rows of Ve (rows 16-31), written once
    {
        v8h one8;
        #pragma unroll
        for (int i = 0; i < 8; ++i) one8[i] = (_Float16)1.f;
        *(v8h*)(Ve + (16 + (tid >> 4)) * 136 + (tid & 15) * 8) = one8;
    }

    // per-128-tile mask flags: bits 4t..4t+3 of any4 <-> tile t has masked tokens
    unsigned long long any4;
    {
        const unsigned long long* mq = (const unsigned long long*)(mask + (size_t)b * NN);
        unsigned long long m0 = mq[lane * 4] | mq[lane * 4 + 1] | mq[lane * 4 + 2] | mq[lane * 4 + 3];
        any4 = __ballot(m0 != 0);
    }

    v16f acc = zero16();

    const int krow = tid >> 1, kpar = tid & 1;   // K staging: 128 rows x 2 halves
    const int vhd = tid >> 4, vg = tid & 15;     // V staging: 16 hd x 16 k-groups of 8
    const _Float16* Kbase = Kr + (size_t)bh * NN * 16;
    const _Float16* Vbase = VT + ((size_t)bh * 16 + vhd) * NN;   // pre-permuted layout
    const unsigned char* mbase = mask + (size_t)b * NN;

    // ---- prologue: prefetch tile 0 into registers ----
    v8h kv = *(const v8h*)(Kbase + (size_t)krow * 16 + kpar * 8);
    v8h vv = *(const v8h*)(Vbase + vg * 8);

    for (int it = 0; it < 16; ++it) {
        __syncthreads();                         // previous tile's reads complete
        // ---- stage current tile from regs ----
        *(v8h*)(Kt + krow * 24 + kpar * 8) = kv;
        *(v8h*)(Ve + vhd * 136 + vg * 8) = vv;   // V pre-permuted: direct copy
        // ---- issue next tile's global loads (latency hides under compute) ----
        if (it < 15) {
            const int k0n = (it + 1) * 128;
            kv = *(const v8h*)(Kbase + (size_t)(k0n + krow) * 16 + kpar * 8);
            vv = *(const v8h*)(Vbase + k0n + vg * 8);
        }
        __syncthreads();                         // staging visible

        const int k0 = it * 128;
        const bool mt = ((any4 >> (it * 4)) & 15ull) != 0;

        #pragma unroll
        for (int kc = 0; kc < 4; ++kc) {
            // A = K rows (row=k-pos=l32 within chunk, k-dim=hd=hi*8+j)
            v8h kf = *(const v8h*)(Kt + (kc * 32 + l32) * 24 + hi * 8);
            v16f sv = mfma32(kf, qf, zero16());   // S^T: col=q=l32, row k=(r&3)+8*(r>>2)+4*hi

            // staged transform: keep all 16 chains live (wide ILP over the
            // quarter-rate exp2/rcp latency)
            float u16[16];
            #pragma unroll
            for (int r = 0; r < 16; ++r) u16[r] = fexp2(sv[r]);          // e^{2z}
            float t16[16];
            #pragma unroll
            for (int r = 0; r < 16; ++r) t16[r] = __builtin_amdgcn_rcpf(u16[r] + 1.f);

            float p[16];
            if (mt) {
                #pragma unroll
                for (int r = 0; r < 16; ++r) {
                    int kk = k0 + kc * 32 + (r >> 2) * 8 + hi * 4 + (r & 3);
                    float ad = mbase[kk] ? -1e30f : C1F;
                    p[r] = fexp2(__builtin_fmaf(t16[r], -C2F, ad));
                }
            } else {
                #pragma unroll
                for (int r = 0; r < 16; ++r)
                    p[r] = fexp2(__builtin_fmaf(t16[r], -C2F, C1F));
            }

            #pragma unroll
            for (int c2 = 0; c2 < 2; ++c2) {
                v8h pa;
                #pragma unroll
                for (int j = 0; j < 8; ++j) pa[j] = (_Float16)p[c2 * 8 + j];
                v8h vf = *(const v8h*)(Ve + l32 * 136 + (kc * 2 + c2) * 16 + hi * 8);
                acc = mfma32(pa, vf, acc);         // rows=q, cols: 0-15 O^T, 16-31 rowsum
            }
        }
    }

    // ---- epilogue ----
    // row sums live in partner lanes (col >= 16); same reg index
    float rs[16];
    #pragma unroll
    for (int r = 0; r < 16; ++r) rs[r] = __shfl_xor(acc[r], 16, 64);

    __syncthreads();                                   // all K-tile reads done: safe to alias
    _Float16* myOt = (_Float16*)smem + w * 768;        // per-wave [32 q][24] halfs over Kt
    if (!(lane & 16)) {                                // lanes holding O columns
        int j = lane & 15;                             // hd
        #pragma unroll
        for (int r = 0; r < 16; ++r) {
            int qr = (r & 3) + 8 * (r >> 2) + 4 * hi;  // q-row within wave tile
            myOt[qr * 24 + j] = (_Float16)(acc[r] * __builtin_amdgcn_rcpf(rs[r]));
        }
    }
    asm volatile("s_waitcnt lgkmcnt(0)" ::: "memory"); // wave-private region: no barrier needed
    v8h ov = *(const v8h*)(myOt + (lane >> 1) * 24 + (lane & 1) * 8);
    *(v8h*)(Obuf + ((size_t)(b * NN + q0 + w * 32 + (lane >> 1)) * 128) + h * 16 + (lane & 1) * 8) = ov;
}

// ---------------- output projection: out = O @ Wout^T (fp32 out), col-split grid.y ----------------
__global__ __launch_bounds__(256) void outproj_kernel(
    const _Float16* __restrict__ Obuf, const float* __restrict__ Wo,
    float* __restrict__ out)
{
    __shared__ __align__(16) _Float16 ob[64][136];
    const int tid = threadIdx.x;
    const int r0 = blockIdx.x * 64;
    const int ct0 = blockIdx.y * 2;                 // 4-way col split: 32 cols/block
    #pragma unroll
    for (int i = 0; i < 8; ++i) {
        int u = tid + i * 256;
        int row = u >> 5, c4 = (u & 31) * 4;
        *(v4h*)&ob[row][c4] = *(const v4h*)(Obuf + (size_t)(r0 + row) * 128 + c4);
    }
    __syncthreads();
    const int w = tid >> 6, lane = tid & 63;
    const int l16 = lane & 15, quad = lane >> 4;
    v4h af[8];
    #pragma unroll
    for (int kt = 0; kt < 8; ++kt)
        af[kt] = *(const v4h*)&ob[w * 16 + l16][kt * 16 + quad * 4];
    v4f acc[2];
    #pragma unroll
    for (int c = 0; c < 2; ++c) acc[c] = zero4();
    #pragma unroll
    for (int kt = 0; kt < 8; ++kt)
        #pragma unroll
        for (int c = 0; c < 2; ++c) {
            v4f wv = *(const v4f*)(Wo + ((ct0 + c) * 16 + l16) * 128 + kt * 16 + quad * 4);
            v4h wf; wf[0]=(_Float16)wv[0]; wf[1]=(_Float16)wv[1]; wf[2]=(_Float16)wv[2]; wf[3]=(_Float16)wv[3];
            acc[c] = mfma16(af[kt], wf, acc[c]);
        }
    #pragma unroll
    for (int c = 0; c < 2; ++c)
        #pragma unroll
        for (int r = 0; r < 4; ++r)
            out[(size_t)(r0 + w * 16 + quad * 4 + r) * 128 + (ct0 + c) * 16 + l16] = acc[c][r];
}

extern "C" void kernel_launch(void* const* d_in, const int* in_sizes, int n_in,
                              void* d_out, int out_size, void* d_ws, size_t ws_size,
                              hipStream_t stream)
{
    const float* q  = (const float*)d_in[0];
    const float* k  = (const float*)d_in[1];
    const float* v  = (const float*)d_in[2];
    const float* Wq = (const float*)d_in[3];
    const float* Wk = (const float*)d_in[4];
    const float* Wv = (const float*)d_in[5];
    const float* Wo = (const float*)d_in[6];
    const unsigned char* mask = (const unsigned char*)d_in[7];
    float* out = (float*)d_out;

    char* ws = (char*)d_ws;
    _Float16* Qr   = (_Float16*)(ws);                 //   4 MB  (B,H,N,16)
    _Float16* Kr   = (_Float16*)(ws + 4194304);       //   4 MB
    _Float16* VTd  = (_Float16*)(ws + 8388608);       //   4 MB  (B,H,16,N) slot-permuted
    _Float16* Obuf = (_Float16*)(ws + 12582912);      //   4 MB  (B*N,128)

    proj_rope_kernel<<<dim3(256, 3), 256, 0, stream>>>(q, k, v, Wq, Wk, Wv, Qr, Kr, VTd);
    attn_kernel<<<1024, 256, 0, stream>>>(Qr, Kr, VTd, mask, Obuf);
    outproj_kernel<<<dim3(256, 4), 256, 0, stream>>>(Obuf, Wo, out);
}

// Round 9
// 186.454 us; speedup vs baseline: 1.0956x; 1.0272x over previous
//
#include <hip/hip_runtime.h>
#include <math.h>

#define BB 8
#define NN 2048
#define DD 128
#define HH 8

typedef _Float16 v4h __attribute__((ext_vector_type(4)));
typedef _Float16 v8h __attribute__((ext_vector_type(8)));
typedef float    v4f __attribute__((ext_vector_type(4)));
typedef float    v16f __attribute__((ext_vector_type(16)));

__device__ __forceinline__ v4f zero4() { v4f z = {0.f, 0.f, 0.f, 0.f}; return z; }
__device__ __forceinline__ v16f zero16() {
    v16f z;
    #pragma unroll
    for (int i = 0; i < 16; ++i) z[i] = 0.f;
    return z;
}

__device__ __forceinline__ v4f mfma16(v4h a, v4h b, v4f c) {
    return __builtin_amdgcn_mfma_f32_16x16x16f16(a, b, c, 0, 0, 0);
}
__device__ __forceinline__ v16f mfma32(v8h a, v8h b, v16f c) {
    return __builtin_amdgcn_mfma_f32_32x32x16_f16(a, b, c, 0, 0, 0);
}

__device__ __forceinline__ float fexp2(float x) {
#if __has_builtin(__builtin_amdgcn_exp2f)
    return __builtin_amdgcn_exp2f(x);          // v_exp_f32 (2^x)
#else
    return __expf(x * 0.69314718055994531f);
#endif
}

// LOGIT_SCALE = ln400/ln50/4 = 0.38288787333
// QSCALE = 2*LOGIT_SCALE*log2(e): folded into Q rope tables so S = log2(e^{2z})
#define QSCALE 1.10478088f
#define C1F 14.426950408889634f   /* 10*log2e */
#define C2F 28.853900817779268f   /* 20*log2e */

// ---------------- fused QKV projection + RoPE (one m per blockIdx.y) ----------------
// W read as fp32 + inline cvt; RoPE/xpos tables computed per block.
// V^T stored with the MFMA slot permutation baked in (swap k-slots 4..7 <-> 8..11
// within each 16-group) so attn can stage V fragments as contiguous v8h.
__global__ __launch_bounds__(256) void proj_rope_kernel(
    const float* __restrict__ q, const float* __restrict__ k, const float* __restrict__ v,
    const float* __restrict__ Wq, const float* __restrict__ Wk, const float* __restrict__ Wv,
    _Float16* __restrict__ Qr, _Float16* __restrict__ Kr, _Float16* __restrict__ VT)
{
    __shared__ __align__(16) _Float16 xb[64][136];
    __shared__ __align__(16) float ctc[64][16];   // cos coefs (pre-scaled)
    __shared__ __align__(16) float cts[64][16];   // sin coefs (pre-scaled)
    const int tid = threadIdx.x;
    const int m  = blockIdx.y;
    const int r0 = blockIdx.x * 64;          // 64 token rows per block
    const int b  = r0 >> 11;
    const int n0 = r0 & 2047;

    const float* s = ((m == 0) ? q : (m == 1) ? k : v) + (size_t)r0 * 128;
    #pragma unroll
    for (int i = 0; i < 8; ++i) {
        int u = tid + i * 256;                       // 2048 float4 chunks
        int row = u >> 5, c4 = (u & 31) * 4;
        v4f f = *(const v4f*)(s + row * 128 + c4);
        v4h hv; hv[0]=(_Float16)f[0]; hv[1]=(_Float16)f[1]; hv[2]=(_Float16)f[2]; hv[3]=(_Float16)f[3];
        *(v4h*)&xb[row][c4] = hv;
    }

    // in-block RoPE/xpos tables (m<2): 512 (token, j) slots, 2 per thread
    if (m < 2) {
        #pragma unroll
        for (int i = 0; i < 2; ++i) {
            int u2 = tid + i * 256;
            int tl = u2 >> 3, j = u2 & 7;
            // invf = 10^(-j/2) via exact 3-select product (no runtime-indexed array)
            float fa = (j & 4) ? 1e-2f : 1.f;
            float fb = (j & 2) ? 1e-1f : 1.f;
            float fc = (j & 1) ? 0.31622776601683794f : 1.f;
            float invf = fa * fb * fc;
            float t = (float)(n0 + tl);
            float freq = t * invf;
            float c = cosf(freq), si = sinf(freq);   // fp32, accurate arg reduction
            float scf = ((float)(2 * j) + 6.4f) / 22.4f;
            float pw  = (t - 1024.0f) / 512.0f;
            float scl = exp2f(pw * log2f(scf));
            float sc  = (m == 0) ? scl * QSCALE : 1.0f / scl;
            float cc = c * sc, ss = si * sc;
            ctc[tl][2 * j]     = cc;
            ctc[tl][2 * j + 1] = cc;
            cts[tl][2 * j]     = ss;
            cts[tl][2 * j + 1] = ss;
        }
    }
    __syncthreads();

    const int w = tid >> 6, lane = tid & 63;
    const int l16 = lane & 15, quad = lane >> 4;

    v4h xf[8];
    #pragma unroll
    for (int kt = 0; kt < 8; ++kt)
        xf[kt] = *(const v4h*)&xb[w * 16 + l16][kt * 16 + quad * 4];
    const float* Wm = (m == 0) ? Wq : (m == 1) ? Wk : Wv;
    v4f acc[8];
    #pragma unroll
    for (int ct = 0; ct < 8; ++ct) acc[ct] = zero4();
    #pragma unroll
    for (int kt = 0; kt < 8; ++kt) {
        #pragma unroll
        for (int ct = 0; ct < 8; ++ct) {
            v4f wv = *(const v4f*)(Wm + (ct * 16 + l16) * 128 + kt * 16 + quad * 4);
            v4h wf; wf[0]=(_Float16)wv[0]; wf[1]=(_Float16)wv[1]; wf[2]=(_Float16)wv[2]; wf[3]=(_Float16)wv[3];
            if (m < 2) acc[ct] = mfma16(wf, xf[kt], acc[ct]);   // D = W * x^T
            else       acc[ct] = mfma16(xf[kt], wf, acc[ct]);   // D = x * W^T
        }
    }
    if (m < 2) {
        const int tl = w * 16 + l16;
        const int n = n0 + tl;
        _Float16* dst = (m == 0 ? Qr : Kr);
        #pragma unroll
        for (int ct = 0; ct < 8; ++ct) {
            v4f cs = *(const v4f*)&ctc[tl][quad * 4];
            v4f sn = *(const v4f*)&cts[tl][quad * 4];
            v4f a = acc[ct];
            v4f rot; rot[0] = -a[1]; rot[1] = a[0]; rot[2] = -a[3]; rot[3] = a[2];
            v4h o;
            #pragma unroll
            for (int r = 0; r < 4; ++r) o[r] = (_Float16)(a[r] * cs[r] + rot[r] * sn[r]);
            *(v4h*)(dst + ((size_t)(b * 8 + ct) * NN + n) * 16 + quad * 4) = o;
        }
    } else {
        // slot-permuted V^T store: within each 16-token group swap quad1<->quad2
        const int quadp = (quad == 1) ? 2 : (quad == 2) ? 1 : quad;
        #pragma unroll
        for (int ct = 0; ct < 8; ++ct) {
            v4f a = acc[ct];
            v4h o;
            #pragma unroll
            for (int r = 0; r < 4; ++r) o[r] = (_Float16)a[r];
            *(v4h*)(VT + ((size_t)(b * 8 + ct) * 16 + l16) * NN + n0 + w * 16 + quadp * 4) = o;
        }
    }
}

// ---------------- fused attention (paired-QK, 32-wide transform ILP) ----------------
// 256 thr / 4 waves / full K; single LDS buffer; reg-prefetch; natural blockIdx.
// Per 128-k tile: two kc-pairs. Each pair: 2 QK^T MFMAs (setprio-wrapped) ->
// one 32-element u->t->p transform (32 independent trans chains: covers the
// quarter-rate exp2/rcp latency that capped VALUBusy at ~72%) -> 4 PV MFMAs.
// Mask via prologue ballot tile-flags; V pre-permuted by proj (direct v8h staging).
__global__ __launch_bounds__(256, 4) void attn_kernel(
    const _Float16* __restrict__ Qr, const _Float16* __restrict__ Kr,
    const _Float16* __restrict__ VT, const unsigned char* __restrict__ mask,
    _Float16* __restrict__ Obuf)
{
    __shared__ __align__(16) char smem[14848];
    _Float16* Kt = (_Float16*)smem;              // [128][24] halfs (row stride 48 B)
    _Float16* Ve = (_Float16*)(smem + 6144);     // [32][136] halfs (rows 0-15 V, 16-31 ones)

    const int bh = blockIdx.x >> 4;              // 64 (b,h)
    const int qt = blockIdx.x & 15;              // 16 q-tiles of 128
    const int b = bh >> 3, h = bh & 7;
    const int q0 = qt * 128;
    const int tid = threadIdx.x;
    const int w = tid >> 6, lane = tid & 63;
    const int l32 = lane & 31, hi = lane >> 5;

    // Q fragment (B-operand): col=q=l32, k(hd)=hi*8+j
    const int qrow = q0 + w * 32 + l32;
    v8h qf = *(const v8h*)(Qr + ((size_t)bh * NN + qrow) * 16 + hi * 8);

    // ones rows of Ve (rows 16-31), written once
    {
        v8h one8;
        #pragma unroll
        for (int i = 0; i < 8; ++i) one8[i] = (_Float16)1.f;
        *(v8h*)(Ve + (16 + (tid >> 4)) * 136 + (tid & 15) * 8) = one8;
    }

    // per-128-tile mask flags: bits 4t..4t+3 of any4 <-> tile t has masked tokens
    unsigned long long any4;
    {
        const unsigned long long* mq = (const unsigned long long*)(mask + (size_t)b * NN);
        unsigned long long m0 = mq[lane * 4] | mq[lane * 4 + 1] | mq[lane * 4 + 2] | mq[lane * 4 + 3];
        any4 = __ballot(m0 != 0);
    }

    v16f acc = zero16();

    const int krow = tid >> 1, kpar = tid & 1;   // K staging: 128 rows x 2 halves
    const int vhd = tid >> 4, vg = tid & 15;     // V staging: 16 hd x 16 k-groups of 8
    const _Float16* Kbase = Kr + (size_t)bh * NN * 16;
    const _Float16* Vbase = VT + ((size_t)bh * 16 + vhd) * NN;   // pre-permuted layout
    const unsigned char* mbase = mask + (size_t)b * NN;

    // ---- prologue: prefetch tile 0 into registers ----
    v8h kv = *(const v8h*)(Kbase + (size_t)krow * 16 + kpar * 8);
    v8h vv = *(const v8h*)(Vbase + vg * 8);

    for (int it = 0; it < 16; ++it) {
        __syncthreads();                         // previous tile's reads complete
        // ---- stage current tile from regs ----
        *(v8h*)(Kt + krow * 24 + kpar * 8) = kv;
        *(v8h*)(Ve + vhd * 136 + vg * 8) = vv;   // V pre-permuted: direct copy
        // ---- issue next tile's global loads (latency hides under compute) ----
        if (it < 15) {
            const int k0n = (it + 1) * 128;
            kv = *(const v8h*)(Kbase + (size_t)(k0n + krow) * 16 + kpar * 8);
            vv = *(const v8h*)(Vbase + k0n + vg * 8);
        }
        __syncthreads();                         // staging visible

        const int k0 = it * 128;
        const bool mt = ((any4 >> (it * 4)) & 15ull) != 0;

        #pragma unroll
        for (int kc2 = 0; kc2 < 2; ++kc2) {
            const int kca = kc2 * 2, kcb = kc2 * 2 + 1;
            // two K fragments, two QK^T MFMAs back-to-back
            v8h kfa = *(const v8h*)(Kt + (kca * 32 + l32) * 24 + hi * 8);
            v8h kfb = *(const v8h*)(Kt + (kcb * 32 + l32) * 24 + hi * 8);
            __builtin_amdgcn_s_setprio(1);
            v16f sva = mfma32(kfa, qf, zero16());   // S^T: col=q=l32, row k=(r&3)+8*(r>>2)+4*hi
            v16f svb = mfma32(kfb, qf, zero16());
            __builtin_amdgcn_s_setprio(0);

            // 32-wide staged transform: all chains independent
            float u32v[32];
            #pragma unroll
            for (int r = 0; r < 16; ++r) { u32v[r] = fexp2(sva[r]); u32v[16 + r] = fexp2(svb[r]); }
            float t32[32];
            #pragma unroll
            for (int r = 0; r < 32; ++r) t32[r] = __builtin_amdgcn_rcpf(u32v[r] + 1.f);
            float p32[32];
            if (mt) {
                #pragma unroll
                for (int r = 0; r < 32; ++r) {
                    int kc = (r < 16) ? kca : kcb;
                    int rr = r & 15;
                    int kk = k0 + kc * 32 + (rr >> 2) * 8 + hi * 4 + (rr & 3);
                    float ad = mbase[kk] ? -1e30f : C1F;
                    p32[r] = fexp2(__builtin_fmaf(t32[r], -C2F, ad));
                }
            } else {
                #pragma unroll
                for (int r = 0; r < 32; ++r)
                    p32[r] = fexp2(__builtin_fmaf(t32[r], -C2F, C1F));
            }

            // pack + 4 PV MFMAs
            v8h pa0, pa1, pb0, pb1;
            #pragma unroll
            for (int j = 0; j < 8; ++j) {
                pa0[j] = (_Float16)p32[j];      pa1[j] = (_Float16)p32[8 + j];
                pb0[j] = (_Float16)p32[16 + j]; pb1[j] = (_Float16)p32[24 + j];
            }
            v8h vfa0 = *(const v8h*)(Ve + l32 * 136 + (kca * 2 + 0) * 16 + hi * 8);
            v8h vfa1 = *(const v8h*)(Ve + l32 * 136 + (kca * 2 + 1) * 16 + hi * 8);
            v8h vfb0 = *(const v8h*)(Ve + l32 * 136 + (kcb * 2 + 0) * 16 + hi * 8);
            v8h vfb1 = *(const v8h*)(Ve + l32 * 136 + (kcb * 2 + 1) * 16 + hi * 8);
            __builtin_amdgcn_s_setprio(1);
            acc = mfma32(pa0, vfa0, acc);        // rows=q, cols: 0-15 O^T, 16-31 rowsum
            acc = mfma32(pa1, vfa1, acc);
            acc = mfma32(pb0, vfb0, acc);
            acc = mfma32(pb1, vfb1, acc);
            __builtin_amdgcn_s_setprio(0);
        }
    }

    // ---- epilogue ----
    // row sums live in partner lanes (col >= 16); same reg index
    float rs[16];
    #pragma unroll
    for (int r = 0; r < 16; ++r) rs[r] = __shfl_xor(acc[r], 16, 64);

    __syncthreads();                                   // all K-tile reads done: safe to alias
    _Float16* myOt = (_Float16*)smem + w * 768;        // per-wave [32 q][24] halfs over Kt
    if (!(lane & 16)) {                                // lanes holding O columns
        int j = lane & 15;                             // hd
        #pragma unroll
        for (int r = 0; r < 16; ++r) {
            int qr = (r & 3) + 8 * (r >> 2) + 4 * hi;  // q-row within wave tile
            myOt[qr * 24 + j] = (_Float16)(acc[r] * __builtin_amdgcn_rcpf(rs[r]));
        }
    }
    asm volatile("s_waitcnt lgkmcnt(0)" ::: "memory"); // wave-private region: no barrier needed
    v8h ov = *(const v8h*)(myOt + (lane >> 1) * 24 + (lane & 1) * 8);
    *(v8h*)(Obuf + ((size_t)(b * NN + q0 + w * 32 + (lane >> 1)) * 128) + h * 16 + (lane & 1) * 8) = ov;
}

// ---------------- output projection: out = O @ Wout^T (fp32 out), col-split grid.y ----------------
__global__ __launch_bounds__(256) void outproj_kernel(
    const _Float16* __restrict__ Obuf, const float* __restrict__ Wo,
    float* __restrict__ out)
{
    __shared__ __align__(16) _Float16 ob[64][136];
    const int tid = threadIdx.x;
    const int r0 = blockIdx.x * 64;
    const int ct0 = blockIdx.y * 2;                 // 4-way col split: 32 cols/block
    #pragma unroll
    for (int i = 0; i < 8; ++i) {
        int u = tid + i * 256;
        int row = u >> 5, c4 = (u & 31) * 4;
        *(v4h*)&ob[row][c4] = *(const v4h*)(Obuf + (size_t)(r0 + row) * 128 + c4);
    }
    __syncthreads();
    const int w = tid >> 6, lane = tid & 63;
    const int l16 = lane & 15, quad = lane >> 4;
    v4h af[8];
    #pragma unroll
    for (int kt = 0; kt < 8; ++kt)
        af[kt] = *(const v4h*)&ob[w * 16 + l16][kt * 16 + quad * 4];
    v4f acc[2];
    #pragma unroll
    for (int c = 0; c < 2; ++c) acc[c] = zero4();
    #pragma unroll
    for (int kt = 0; kt < 8; ++kt)
        #pragma unroll
        for (int c = 0; c < 2; ++c) {
            v4f wv = *(const v4f*)(Wo + ((ct0 + c) * 16 + l16) * 128 + kt * 16 + quad * 4);
            v4h wf; wf[0]=(_Float16)wv[0]; wf[1]=(_Float16)wv[1]; wf[2]=(_Float16)wv[2]; wf[3]=(_Float16)wv[3];
            acc[c] = mfma16(af[kt], wf, acc[c]);
        }
    #pragma unroll
    for (int c = 0; c < 2; ++c)
        #pragma unroll
        for (int r = 0; r < 4; ++r)
            out[(size_t)(r0 + w * 16 + quad * 4 + r) * 128 + (ct0 + c) * 16 + l16] = acc[c][r];
}

extern "C" void kernel_launch(void* const* d_in, const int* in_sizes, int n_in,
                              void* d_out, int out_size, void* d_ws, size_t ws_size,
                              hipStream_t stream)
{
    const float* q  = (const float*)d_in[0];
    const float* k  = (const float*)d_in[1];
    const float* v  = (const float*)d_in[2];
    const float* Wq = (const float*)d_in[3];
    const float* Wk = (const float*)d_in[4];
    const float* Wv = (const float*)d_in[5];
    const float* Wo = (const float*)d_in[6];
    const unsigned char* mask = (const unsigned char*)d_in[7];
    float* out = (float*)d_out;

    char* ws = (char*)d_ws;
    _Float16* Qr   = (_Float16*)(ws);                 //   4 MB  (B,H,N,16)
    _Float16* Kr   = (_Float16*)(ws + 4194304);       //   4 MB
    _Float16* VTd  = (_Float16*)(ws + 8388608);       //   4 MB  (B,H,16,N) slot-permuted
    _Float16* Obuf = (_Float16*)(ws + 12582912);      //   4 MB  (B*N,128)

    proj_rope_kernel<<<dim3(256, 3), 256, 0, stream>>>(q, k, v, Wq, Wk, Wv, Qr, Kr, VTd);
    attn_kernel<<<1024, 256, 0, stream>>>(Qr, Kr, VTd, mask, Obuf);
    outproj_kernel<<<dim3(256, 4), 256, 0, stream>>>(Obuf, Wo, out);
}